// Round 2
// baseline (1488.183 us; speedup 1.0000x reference)
//
#include <hip/hip_runtime.h>
#include <math.h>

typedef unsigned short u16;
typedef unsigned int   u32;
typedef float f32x4 __attribute__((ext_vector_type(4)));
typedef short s16x8 __attribute__((ext_vector_type(8)));

__device__ __forceinline__ u16 f2bf(float x) {
    u32 u = __float_as_uint(x);
    u32 r = (u + 0x7FFFu + ((u >> 16) & 1u)) >> 16;
    return (u16)r;
}

// 8x fp32 -> 8x bf16 via v_cvt_pk_bf16_f32 (RNE), 4 instructions
__device__ __forceinline__ s16x8 pack8(float4 a, float4 b) {
    union { u32 w[4]; s16x8 v; } r;
    asm("v_cvt_pk_bf16_f32 %0, %1, %2" : "=v"(r.w[0]) : "v"(a.x), "v"(a.y));
    asm("v_cvt_pk_bf16_f32 %0, %1, %2" : "=v"(r.w[1]) : "v"(a.z), "v"(a.w));
    asm("v_cvt_pk_bf16_f32 %0, %1, %2" : "=v"(r.w[2]) : "v"(b.x), "v"(b.y));
    asm("v_cvt_pk_bf16_f32 %0, %1, %2" : "=v"(r.w[3]) : "v"(b.z), "v"(b.w));
    return r.v;
}

__device__ __forceinline__ float tanh_fast(float x) {
    float e = __expf(2.0f * x);
    return 1.0f - __fdividef(2.0f, e + 1.0f);
}

// ---------------- Wv -> bf16 convert ----------------
__global__ __launch_bounds__(256) void bf16cvt_kernel(
    const float* __restrict__ src, u16* __restrict__ dst)
{
    const int i = (blockIdx.x * 256 + threadIdx.x) * 4;
    float4 v = *(const float4*)(src + i);
    u32 p0 = (u32)f2bf(v.x) | ((u32)f2bf(v.y) << 16);
    u32 p1 = (u32)f2bf(v.z) | ((u32)f2bf(v.w) << 16);
    *(uint2*)((char*)dst + (size_t)i * 2) = make_uint2(p0, p1);
}

// ---------------- c[b,a] = key @ Wh^T + bh + bv ----------------
__global__ __launch_bounds__(256) void cvec_kernel(
    const float* __restrict__ key,
    const float* __restrict__ Wh,  const float* __restrict__ bh,  const float* __restrict__ bv,
    const float* __restrict__ Wh2, const float* __restrict__ bh2, const float* __restrict__ bv2,
    float* __restrict__ c1, float* __restrict__ c2)
{
    const int bid = blockIdx.x;
    const int which = bid >> 7;
    const int rem = bid & 127;
    const int b = rem >> 1;
    const int a0 = (rem & 1) * 256;
    const float* W   = which ? Wh2 : Wh;
    const float* bhp = which ? bh2 : bh;
    const float* bvp = which ? bv2 : bv;
    float* c = which ? c2 : c1;
    __shared__ float kv[1024];
    const int t = threadIdx.x;
    #pragma unroll
    for (int j = 0; j < 4; ++j) kv[t + j * 256] = key[(size_t)b * 1024 + t + j * 256];
    __syncthreads();
    const int a = a0 + t;
    const float* wr = W + (size_t)a * 1024;
    float acc = 0.f;
    for (int h = 0; h < 1024; h += 4) {
        float4 w = *(const float4*)(wr + h);
        acc += kv[h] * w.x + kv[h + 1] * w.y + kv[h + 2] * w.z + kv[h + 3] * w.w;
    }
    c[(size_t)b * 512 + a] = acc + bhp[a] + bvp[a];
}

// ---------------- scores[b,l] = sum_a wa[a]*tanh(c[b,a] + (X@Wv^T)[b,l,a]) ----------------
// X: (Mtot,1024) fp32 row-major; Wb: (512,1024) bf16 row-major.
// Block: 128 M-rows, internal loop over 4 A-chunks of 128 (X re-read hits L3).
// 4 waves, each owns 32 unique M-rows x full 128-A-chunk -> plain stores, no atomics.
__global__ __launch_bounds__(256, 2) void scores_kernel(
    const float* __restrict__ X, const u16* __restrict__ Wb,
    const float* __restrict__ cvec, const float* __restrict__ wa,
    float* __restrict__ scores, const int L)
{
    __shared__ u16 As[4096];   // [128][32]
    __shared__ u16 Bs[4096];   // [128][32]
    const int t = threadIdx.x;
    const int lane = t & 63;
    const int wave = t >> 6;
    const int m0 = blockIdx.x * 128;
    const int wm = wave * 32;
    const int lr = lane & 15;
    const int kg = lane >> 4;

    const int srow = t >> 2;
    const int skk  = (t & 3) * 8;
    const float* xp  = X  + (size_t)(m0 + srow) * 1024 + skk;
    const float* xp2 = xp + (size_t)64 * 1024;

    const int b = m0 / L;
    const int lbase = m0 % L;

    float stot[2][4];
    #pragma unroll
    for (int m = 0; m < 2; ++m)
        #pragma unroll
        for (int r = 0; r < 4; ++r) stot[m][r] = 0.f;

    for (int a0 = 0; a0 < 512; a0 += 128) {
        const u16* wp  = Wb + (size_t)(a0 + srow) * 1024 + skk;
        const u16* wp2 = wp + (size_t)64 * 1024;

        f32x4 acc[2][8];
        #pragma unroll
        for (int m = 0; m < 2; ++m)
            #pragma unroll
            for (int n = 0; n < 8; ++n)
                acc[m][n] = (f32x4){0.f, 0.f, 0.f, 0.f};

        for (int k0 = 0; k0 < 1024; k0 += 32) {
            float4 a0v = *(const float4*)(xp  + k0);
            float4 a1v = *(const float4*)(xp  + k0 + 4);
            float4 a2v = *(const float4*)(xp2 + k0);
            float4 a3v = *(const float4*)(xp2 + k0 + 4);
            s16x8 b0v = *(const s16x8*)(wp  + k0);
            s16x8 b1v = *(const s16x8*)(wp2 + k0);
            __syncthreads();
            *(s16x8*)&As[8 * t]        = pack8(a0v, a1v);
            *(s16x8*)&As[2048 + 8 * t] = pack8(a2v, a3v);
            *(s16x8*)&Bs[8 * t]        = b0v;
            *(s16x8*)&Bs[2048 + 8 * t] = b1v;
            __syncthreads();
            s16x8 af[2], bf[8];
            #pragma unroll
            for (int m = 0; m < 2; ++m)
                af[m] = *(const s16x8*)&As[(wm + m * 16 + lr) * 32 + kg * 8];
            #pragma unroll
            for (int n = 0; n < 8; ++n)
                bf[n] = *(const s16x8*)&Bs[(n * 16 + lr) * 32 + kg * 8];
            #pragma unroll
            for (int m = 0; m < 2; ++m)
                #pragma unroll
                for (int n = 0; n < 8; ++n)
                    acc[m][n] = __builtin_amdgcn_mfma_f32_16x16x32_bf16(af[m], bf[n], acc[m][n], 0, 0, 0);
        }

        // epilogue for this a-chunk: accumulate wa*tanh(v+c) per lane (a-subset = lr + n*16)
        float wav[8], cv[8];
        #pragma unroll
        for (int n = 0; n < 8; ++n) {
            int ag = a0 + n * 16 + lr;
            wav[n] = wa[ag];
            cv[n]  = cvec[(size_t)b * 512 + ag];
        }
        #pragma unroll
        for (int m = 0; m < 2; ++m)
            #pragma unroll
            for (int r = 0; r < 4; ++r) {
                float s = 0.f;
                #pragma unroll
                for (int n = 0; n < 8; ++n)
                    s += wav[n] * tanh_fast(acc[m][n][r] + cv[n]);
                stot[m][r] += s;
            }
    }

    // reduce over the 16 a-lanes once, then plain store (rows are wave-exclusive)
    #pragma unroll
    for (int m = 0; m < 2; ++m)
        #pragma unroll
        for (int r = 0; r < 4; ++r) {
            float s = stot[m][r];
            s += __shfl_xor(s, 1);
            s += __shfl_xor(s, 2);
            s += __shfl_xor(s, 4);
            s += __shfl_xor(s, 8);
            if (lr == 0) {
                int row = lbase + wm + m * 16 + kg * 4 + r;
                scores[(size_t)b * L + row] = s;
            }
        }
}

// ---------------- softmax over L, in place ----------------
__global__ __launch_bounds__(256) void softmax_kernel(float* __restrict__ s, const int L)
{
    const int b = blockIdx.x;
    float* row = s + (size_t)b * L;
    const int t = threadIdx.x;
    const int lane = t & 63;
    const int wave = t >> 6;
    __shared__ float red[8];
    float v[8];
    #pragma unroll
    for (int j = 0; j < 8; ++j) {
        int i = t + j * 256;
        v[j] = (i < L) ? row[i] : -INFINITY;
    }
    float mx = v[0];
    #pragma unroll
    for (int j = 1; j < 8; ++j) mx = fmaxf(mx, v[j]);
    #pragma unroll
    for (int o = 1; o < 64; o <<= 1) mx = fmaxf(mx, __shfl_xor(mx, o));
    if (lane == 0) red[wave] = mx;
    __syncthreads();
    mx = fmaxf(fmaxf(red[0], red[1]), fmaxf(red[2], red[3]));
    float sum = 0.f;
    #pragma unroll
    for (int j = 0; j < 8; ++j) {
        int i = t + j * 256;
        v[j] = (i < L) ? __expf(v[j] - mx) : 0.f;
        sum += v[j];
    }
    #pragma unroll
    for (int o = 1; o < 64; o <<= 1) sum += __shfl_xor(sum, o);
    if (lane == 0) red[4 + wave] = sum;
    __syncthreads();
    sum = red[4] + red[5] + red[6] + red[7];
    float inv = 1.0f / sum;
    #pragma unroll
    for (int j = 0; j < 8; ++j) {
        int i = t + j * 256;
        if (i < L) row[i] = v[j] * inv;
    }
}

// ---------------- att[b,f] = sum_l alpha[b,l] * X[b,l,f] ----------------
__global__ __launch_bounds__(256) void att_kernel(
    const float* __restrict__ X, const float* __restrict__ alpha,
    float* __restrict__ att, const int L)
{
    const int b = blockIdx.x;
    const int c0 = blockIdx.y * 128;
    const float* Xb = X + ((size_t)b * L + c0) * 1024;
    const float* al = alpha + (size_t)b * L + c0;
    const int t = threadIdx.x;
    float4 acc = {0.f, 0.f, 0.f, 0.f};
    #pragma unroll 4
    for (int l = 0; l < 128; ++l) {
        float a = al[l];
        float4 x = *(const float4*)(Xb + (size_t)l * 1024 + t * 4);
        acc.x += a * x.x; acc.y += a * x.y; acc.z += a * x.z; acc.w += a * x.w;
    }
    float* dst = att + (size_t)b * 1024 + t * 4;
    atomicAdd(dst + 0, acc.x);
    atomicAdd(dst + 1, acc.y);
    atomicAdd(dst + 2, acc.z);
    atomicAdd(dst + 3, acc.w);
}

// ---------------- gate + blend ----------------
__global__ __launch_bounds__(256) void gate_kernel(
    const float* __restrict__ att1, const float* __restrict__ att2,
    const float* __restrict__ key, const float* __restrict__ Wg,
    const float* __restrict__ bg, float* __restrict__ out)
{
    const int t = threadIdx.x;
    const int bl = t >> 6;
    const int fl = t & 63;
    const int b = blockIdx.x * 4 + bl;
    const int f = blockIdx.y * 64 + fl;
    __shared__ float gin[4][72];
    const float* wrow = Wg + (size_t)f * 3072;
    float acc = 0.f;
    for (int k0 = 0; k0 < 3072; k0 += 64) {
        int k = k0 + fl;
        float gv;
        if (k < 1024)      gv = att1[(size_t)b * 1024 + k];
        else if (k < 2048) gv = key [(size_t)b * 1024 + k - 1024];
        else               gv = att2[(size_t)b * 1024 + k - 2048];
        __syncthreads();
        gin[bl][fl] = gv;
        __syncthreads();
        #pragma unroll
        for (int kk = 0; kk < 64; kk += 4) {
            float4 w = *(const float4*)(wrow + k0 + kk);
            float4 g = *(const float4*)&gin[bl][kk];
            acc += g.x * w.x + g.y * w.y + g.z * w.z + g.w * w.w;
        }
    }
    float x = acc + bg[f];
    float gs = __fdividef(1.0f, 1.0f + __expf(-x));
    float a1 = att1[(size_t)b * 1024 + f];
    float a2 = att2[(size_t)b * 1024 + f];
    out[(size_t)b * 1024 + f] = gs * a1 + (1.0f - gs) * a2;
}

extern "C" void kernel_launch(void* const* d_in, const int* in_sizes, int n_in,
                              void* d_out, int out_size, void* d_ws, size_t ws_size,
                              hipStream_t stream)
{
    const float* feats   = (const float*)d_in[0];
    const float* cluster = (const float*)d_in[1];
    const float* key     = (const float*)d_in[2];
    const float* Wv      = (const float*)d_in[3];
    const float* bv      = (const float*)d_in[4];
    const float* Wh      = (const float*)d_in[5];
    const float* bh      = (const float*)d_in[6];
    const float* wa      = (const float*)d_in[7];
    const float* Wv2     = (const float*)d_in[8];
    const float* bv2     = (const float*)d_in[9];
    const float* Wh2     = (const float*)d_in[10];
    const float* bh2     = (const float*)d_in[11];
    const float* wa2     = (const float*)d_in[12];
    const float* Wg      = (const float*)d_in[13];
    const float* bg      = (const float*)d_in[14];
    float* out = (float*)d_out;

    char* ws = (char*)d_ws;
    u16*   Wvb     = (u16*)  (ws + 0);
    u16*   Wv2b    = (u16*)  (ws + 1048576);
    float* c1      = (float*)(ws + 2097152);
    float* c2      = (float*)(ws + 2228224);
    float* scores1 = (float*)(ws + 2359296);
    float* scores2 = (float*)(ws + 2883584);
    float* att1    = (float*)(ws + 2916352);
    float* att2    = (float*)(ws + 3178496);

    // zero only the atomic-accumulation regions (att1, att2)
    hipMemsetAsync(ws + 2916352, 0, 524288, stream);

    bf16cvt_kernel<<<512, 256, 0, stream>>>(Wv,  Wvb);
    bf16cvt_kernel<<<512, 256, 0, stream>>>(Wv2, Wv2b);
    cvec_kernel<<<256, 256, 0, stream>>>(key, Wh, bh, bv, Wh2, bh2, bv2, c1, c2);

    scores_kernel<<<1024, 256, 0, stream>>>(feats,   Wvb,  c1, wa,  scores1, 2048);
    scores_kernel<<<64,   256, 0, stream>>>(cluster, Wv2b, c2, wa2, scores2, 128);

    softmax_kernel<<<64, 256, 0, stream>>>(scores1, 2048);
    softmax_kernel<<<64, 256, 0, stream>>>(scores2, 128);

    att_kernel<<<dim3(64, 16), 256, 0, stream>>>(feats,   scores1, att1, 2048);
    att_kernel<<<dim3(64, 1),  256, 0, stream>>>(cluster, scores2, att2, 128);

    gate_kernel<<<dim3(16, 16), 256, 0, stream>>>(att1, att2, key, Wg, bg, out);
}